// Round 10
// baseline (335.386 us; speedup 1.0000x reference)
//
#include <hip/hip_runtime.h>

// Problem constants
#define NIMG 32
#define H 112
#define W 112
#define CI 64
#define CO 128
#define HP 114            // padded rows/cols
// K = 3*3*64 = 576 -> 9 taps of K=64 (i8 MFMA 16x16x64), CI==64 = one step per tap

typedef __attribute__((ext_vector_type(8))) __bf16 bf16x8;
typedef __attribute__((ext_vector_type(4))) float f32x4;
typedef __attribute__((ext_vector_type(4))) short short4v;
typedef __attribute__((ext_vector_type(4))) int int4v;

// ---- fixed-point quantizers ----
__device__ __forceinline__ short q8bits(float v) {        // bf16-int (fallback path)
    float t = rintf(v * 128.0f);              // round-half-even == np.round
    t = fminf(fmaxf(t, -128.0f), 127.0f);
    union { float f; unsigned u; } cv; cv.f = t;
    return (short)(cv.u >> 16);
}
__device__ __forceinline__ int q8i(float v) {             // int in [-128,127]
    float t = rintf(v * 128.0f);
    t = fminf(fmaxf(t, -128.0f), 127.0f);
    return (int)t;
}

// ---------------- i8 weight pack (verified R2 layout) ----------------
// bp[((kk*8+nt)*64+l)*16+j] = q(w[(kk*64+(l>>4)*16+j)*128 + nt*16+(l&15)])
__global__ __launch_bounds__(256) void prep_pack(const float* __restrict__ w,
                                                 signed char* __restrict__ bp) {
    int idx = blockIdx.x * 256 + threadIdx.x;   // grid 288 -> exactly 73728
    int j  = idx & 15;
    int l  = (idx >> 4) & 63;
    int nt = (idx >> 10) & 7;
    int kk = idx >> 13;
    int k = kk * 64 + (l >> 4) * 16 + j;
    int n = nt * 16 + (l & 15);
    bp[idx] = (signed char)q8i(w[k * CO + n]);
}

// ---------------- activation quant into PADDED layout ----------------
// xqp[n][hp][c][ci], hp,c in [0,114): zeros at hp=0,113 and c=0,113;
// interior (hp,c) = q8i(x[n][hp-1][c-1][ci]). Padding rewritten every
// iteration (harness re-poisons the workspace).
__global__ __launch_bounds__(256) void prep_x(const float* __restrict__ x,
                                              signed char* __restrict__ xqp) {
    int p   = blockIdx.x;                     // grid 32*114
    int tid = threadIdx.x;
    int n  = p / HP;
    int hp = p - n * HP;
    size_t rb = ((size_t)(n * HP + hp)) * (HP * 64);
    if (hp == 0 || hp == HP - 1) {            // zero pad rows (7296 B = 456 x 16B)
        for (int t = tid; t < 456; t += 256)
            *(int4v*)&xqp[rb + (size_t)t * 16] = (int4v){0, 0, 0, 0};
        return;
    }
    if (tid < 8) {                            // zero halo cols 0 & 113 (64B each)
        int c = (tid & 4) ? (HP - 1) : 0;
        *(int4v*)&xqp[rb + c * 64 + (tid & 3) * 16] = (int4v){0, 0, 0, 0};
    }
    const float* src = x + ((size_t)(n * H + hp - 1) * W) * CI;   // input row hp-1
    #pragma unroll
    for (int k = 0; k < 7; ++k) {             // 7*1024 = 7168 floats = one row
        float4 v = *(const float4*)&src[k * 1024 + tid * 4];
        int b = (q8i(v.x) & 255) | ((q8i(v.y) & 255) << 8) |
                ((q8i(v.z) & 255) << 16) | (q8i(v.w) << 24);
        int L = k * 1024 + tid * 4;           // byte offset within unpadded row
        *(int*)&xqp[rb + 64 + L] = b;         // +64 skips col-0 halo
    }
}

// ---------------- Direct conv (i8): NO LDS, NO barrier ----------------
// A-fragment for (tap,mt) is a contiguous coalesced 1KB of padded xq:
//   lane l (l15=l&15, hi=l>>4) reads 16B at ((n*114+h+r)*114 + s+l15+mt*16)*64 + hi*16
// -- identical fragment bytes to the verified R7 staged path (padded col c ==
// input col c-1). Padding makes every access in-bounds, zero contribution.
// 4 waves share the A row (L1 reuse, 21.9KB working set), each owns a 32-co
// quarter. Pure load->MFMA->store, one flat dependence graph; 8-12
// independent waves/CU hide L1/L2 latency.
// Lessons kept: no __launch_bounds__ waves hint (R5/R6 spill), B inline per kk.
__global__ __launch_bounds__(256) void conv_dir(const signed char* __restrict__ xqp,
                                                const signed char* __restrict__ bp,
                                                float* __restrict__ out) {
    int bid0 = blockIdx.x;
    int bid = (bid0 & 7) * 448 + (bid0 >> 3);   // XCD swizzle (3584 = 8*448, bijective)
    int n = bid / H;
    int h = bid - n * H;
    int tid  = threadIdx.x;
    int lane = tid & 63;
    int wave = tid >> 6;
    int lane15 = lane & 15;
    int hi     = lane >> 4;
    int nt0    = wave * 2;
    const int4v* bp4 = (const int4v*)bp;

    // per-lane A base: padded row h+0, col lane15, ci hi*16
    const signed char* ab0 =
        xqp + (((size_t)(n * HP + h)) * HP + lane15) * 64 + hi * 16;

    int4v acc[7][2];
    #pragma unroll
    for (int mt = 0; mt < 7; ++mt) {
        acc[mt][0] = (int4v){0, 0, 0, 0};
        acc[mt][1] = (int4v){0, 0, 0, 0};
    }

    #pragma unroll
    for (int r = 0; r < 3; ++r) {
        #pragma unroll
        for (int s = 0; s < 3; ++s) {
            int kk = r * 3 + s;
            int4v b0 = bp4[(kk * 8 + nt0    ) * 64 + lane];
            int4v b1 = bp4[(kk * 8 + nt0 + 1) * 64 + lane];
            const signed char* ab = ab0 + (r * HP + s) * 64;
            #pragma unroll
            for (int mt = 0; mt < 7; ++mt) {
                int4v a = *(const int4v*)(ab + mt * 1024);
                acc[mt][0] = __builtin_amdgcn_mfma_i32_16x16x64_i8(a, b0, acc[mt][0], 0, 0, 0);
                acc[mt][1] = __builtin_amdgcn_mfma_i32_16x16x64_i8(a, b1, acc[mt][1], 0, 0, 0);
            }
        }
    }

    // ---- epilogue: out = floor(S/128)/128, exact in int ----
    float* orow = out + (size_t)((n * H + h) * W) * CO;
    int co0  = wave * 32 + lane15;
    int rowb = hi * 4;
    #pragma unroll
    for (int mt = 0; mt < 7; ++mt)
        #pragma unroll
        for (int t = 0; t < 2; ++t)
            #pragma unroll
            for (int rg = 0; rg < 4; ++rg) {
                int m = mt * 16 + rowb + rg;
                orow[m * CO + co0 + t * 16] =
                    (float)(acc[mt][t][rg] >> 7) * 0.0078125f;
            }
}

// ---------------- bf16 weight pack (fallback path only) ----------------
__global__ __launch_bounds__(256) void quant_pack_w(const float* __restrict__ w,
                                                    short* __restrict__ bp) {
    int idx = blockIdx.x * 256 + threadIdx.x;   // grid sized exactly 73728
    int j    = idx & 7;
    int lane = (idx >> 3) & 63;
    int nt   = (idx >> 9) & 7;
    int kt   = idx >> 12;
    int k = kt * 32 + (lane >> 4) * 8 + j;
    int n = nt * 16 + (lane & 15);
    bp[idx] = q8bits(w[k * CO + n]);
}

// ---------------- R1 fallback (tiny ws): verified exact ----------------
#define LDSW 114
#define LDST 72
__global__ __launch_bounds__(256) void conv_fb(const float* __restrict__ x,
                                               const short* __restrict__ bp,
                                               float* __restrict__ out) {
    __shared__ short xs[3 * LDSW * LDST];
    int bid = blockIdx.x;
    int n = bid / H;
    int h = bid - n * H;
    int tid = threadIdx.x;
    const float* xin = x + (size_t)n * (H * W * CI);
    for (int r = 0; r < 3; ++r) {
        int hrow = h + r - 1;
        bool rowok = ((unsigned)hrow < (unsigned)H);
        const float* srow = xin + (size_t)hrow * (W * CI);
        for (int t = tid; t < LDSW * 16; t += 256) {
            int c = t >> 4;
            int ci4 = (t & 15) << 2;
            int wcol = c - 1;
            float4 v = {0.f, 0.f, 0.f, 0.f};
            if (rowok && (unsigned)wcol < (unsigned)W)
                v = *(const float4*)&srow[wcol * CI + ci4];
            short4v sv;
            sv.x = q8bits(v.x); sv.y = q8bits(v.y);
            sv.z = q8bits(v.z); sv.w = q8bits(v.w);
            *(short4v*)&xs[(r * LDSW + c) * LDST + ci4] = sv;
        }
    }
    __syncthreads();
    int lane = tid & 63;
    int wave = tid >> 6;
    int laneoff = (lane & 15) * LDST + (lane >> 4) * 8;
    const bf16x8* bfr = (const bf16x8*)bp;
    int nt0 = wave * 2;
    f32x4 acc[7][2];
    #pragma unroll
    for (int mt = 0; mt < 7; ++mt) {
        acc[mt][0] = (f32x4){0.f, 0.f, 0.f, 0.f};
        acc[mt][1] = (f32x4){0.f, 0.f, 0.f, 0.f};
    }
    #pragma unroll
    for (int kk = 0; kk < 18; ++kk) {
        int rs = kk >> 1;
        int r = rs / 3;
        int s = rs - r * 3;
        bf16x8 b0 = bfr[(kk * 8 + nt0    ) * 64 + lane];
        bf16x8 b1 = bfr[(kk * 8 + nt0 + 1) * 64 + lane];
        int abase = (r * LDSW + s) * LDST + (kk & 1) * 32 + laneoff;
        #pragma unroll
        for (int mt = 0; mt < 7; ++mt) {
            bf16x8 a = *(const bf16x8*)&xs[abase + mt * 16 * LDST];
            acc[mt][0] = __builtin_amdgcn_mfma_f32_16x16x32_bf16(a, b0, acc[mt][0], 0, 0, 0);
            acc[mt][1] = __builtin_amdgcn_mfma_f32_16x16x32_bf16(a, b1, acc[mt][1], 0, 0, 0);
        }
    }
    float* orow = out + (size_t)(n * H + h) * (W * CO);
    int colc = wave * 32 + (lane & 15);
    int rowb = (lane >> 4) * 4;
    #pragma unroll
    for (int mt = 0; mt < 7; ++mt)
        #pragma unroll
        for (int t2 = 0; t2 < 2; ++t2)
            #pragma unroll
            for (int rg = 0; rg < 4; ++rg) {
                int m = mt * 16 + rowb + rg;
                orow[m * CO + colc + t2 * 16] =
                    floorf(acc[mt][t2][rg] * 0.0078125f) * 0.0078125f;
            }
}

extern "C" void kernel_launch(void* const* d_in, const int* in_sizes, int n_in,
                              void* d_out, int out_size, void* d_ws, size_t ws_size,
                              hipStream_t stream) {
    const float* x = (const float*)d_in[0];     // (32,112,112,64) fp32 NHWC
    const float* w = (const float*)d_in[1];     // (3,3,64,128) fp32 HWIO
    float* out = (float*)d_out;                 // (32,112,112,128) fp32

    const size_t BPI8_BYTES = 73728;            // 576*128 i8 packed weights
    const size_t XQP_BYTES  = (size_t)NIMG * HP * HP * CI;   // 26,615,808 B padded

    if (ws_size >= BPI8_BYTES + XQP_BYTES) {
        signed char* bp8 = (signed char*)d_ws;
        signed char* xqp = (signed char*)d_ws + BPI8_BYTES;
        prep_pack<<<288, 256, 0, stream>>>(w, bp8);
        prep_x<<<NIMG * HP, 256, 0, stream>>>(x, xqp);          // 3648 blocks
        conv_dir<<<NIMG * H, 256, 0, stream>>>(xqp, bp8, out);  // 3584 blocks
    } else {
        short* bp = (short*)d_ws;               // 147456 B bf16 packed weights
        quant_pack_w<<<288, 256, 0, stream>>>(w, bp);
        conv_fb<<<NIMG * H, 256, 0, stream>>>(x, bp, out);
    }
}